// Round 1
// baseline (242.927 us; speedup 1.0000x reference)
//
#include <hip/hip_runtime.h>
#include <math.h>

#define IN_NUM 1152
#define IN_DIM 8
#define OUT_NUM 10
#define OUT_DIM 16
#define BATCH 256
#define KTOT (IN_NUM * IN_DIM)   // 9216

// ---------------------------------------------------------------------------
// K0: transpose W[i][j][o][d] -> Wt[j][k][o], k = d*IN_NUM + i
// grid 1152, block 128 (t = o*8+d)
// ---------------------------------------------------------------------------
__global__ __launch_bounds__(128) void k_transpose_W(const float* __restrict__ W,
                                                     float* __restrict__ Wt) {
    const int i = blockIdx.x;
    const int t = threadIdx.x;          // 0..127
    const int o = t >> 3, d = t & 7;
    for (int j = 0; j < OUT_NUM; ++j) {
        float w = W[(size_t)i * 1280 + j * 128 + o * 8 + d];   // ((i*10+j)*16+o)*8+d
        Wt[(size_t)j * KTOT * OUT_DIM + (size_t)(d * IN_NUM + i) * OUT_DIM + o] = w;
    }
}

// ---------------------------------------------------------------------------
// K1: row softmax of b[i][j] over j -> Ct[j][i]  (transposed for coalesced GEMM reads)
// ---------------------------------------------------------------------------
__global__ __launch_bounds__(256) void k_softmax(const float* __restrict__ b,
                                                 float* __restrict__ Ct) {
    const int i = blockIdx.x * blockDim.x + threadIdx.x;
    if (i >= IN_NUM) return;
    float v[OUT_NUM];
    float m = -INFINITY;
    for (int j = 0; j < OUT_NUM; ++j) { v[j] = b[i * OUT_NUM + j]; m = fmaxf(m, v[j]); }
    float ssum = 0.f;
    for (int j = 0; j < OUT_NUM; ++j) { v[j] = expf(v[j] - m); ssum += v[j]; }
    const float inv = 1.0f / ssum;
    for (int j = 0; j < OUT_NUM; ++j) Ct[j * IN_NUM + i] = v[j] * inv;
}

// ---------------------------------------------------------------------------
// K2: s_j[o,b] += sum_k (c[k]*Wt_j[k,o]) * x[b,k]   (k restricted to one d-slice)
// grid (10 j, 8 d, 4 b-tiles), block 256.  atomicAdd accumulate over d-splits.
// thread t: b = b0 + (t&63), o = (t>>6)*4 .. +3
// ---------------------------------------------------------------------------
__global__ __launch_bounds__(256) void k_gemm_s(const float* __restrict__ x,
                                                const float* __restrict__ Wt,
                                                const float* __restrict__ Ct,
                                                float* __restrict__ s) {
    const int j = blockIdx.x, d = blockIdx.y;
    const int b0 = blockIdx.z * 64;
    __shared__ float Xs[64][65];      // [b][k], pad -> 2-way bank alias (free)
    __shared__ float Ws[64][16];      // [k][o], read as wave-uniform broadcast
    const int t  = threadIdx.x;
    const int bl = t & 63;
    const int og = t >> 6;            // 0..3

    const float* Wtj = Wt + (size_t)j * KTOT * OUT_DIM;
    const float* Ctj = Ct + j * IN_NUM;

    float acc0 = 0.f, acc1 = 0.f, acc2 = 0.f, acc3 = 0.f;

    for (int kt = 0; kt < 18; ++kt) {          // 18*64 = 1152 i's per d-slice
        const int i0 = kt * 64;
        // --- load Wt tile: 64k x 16o = 1024 floats, 4/thread, contiguous
        {
            const int idx = t * 4;             // flat = k*16 + o
            float4 wv = *reinterpret_cast<const float4*>(
                Wtj + (size_t)(d * IN_NUM + i0) * OUT_DIM + idx);
            const int kk = idx >> 4, oo = idx & 15;
            *reinterpret_cast<float4*>(&Ws[kk][oo]) = wv;
        }
        // --- load X tile 64b x 64k, folding c[k] in at load time
        #pragma unroll
        for (int r = 0; r < 16; ++r) {
            const int f  = r * 256 + t;        // 0..4095
            const int bb = f >> 6, kk = f & 63;
            const float xv = x[(size_t)(b0 + bb) * KTOT + d * IN_NUM + i0 + kk];
            Xs[bb][kk] = xv * Ctj[i0 + kk];
        }
        __syncthreads();
        #pragma unroll
        for (int kk = 0; kk < 64; ++kk) {
            const float xv = Xs[bl][kk];
            float4 wv = *reinterpret_cast<const float4*>(&Ws[kk][og * 4]); // broadcast
            acc0 += xv * wv.x; acc1 += xv * wv.y;
            acc2 += xv * wv.z; acc3 += xv * wv.w;
        }
        __syncthreads();
    }
    // s layout [j][o][b]
    float* sp = s + ((size_t)j * OUT_DIM + og * 4) * BATCH + (b0 + bl);
    atomicAdd(sp + 0 * BATCH, acc0);
    atomicAdd(sp + 1 * BATCH, acc1);
    atomicAdd(sp + 2 * BATCH, acc2);
    atomicAdd(sp + 3 * BATCH, acc3);
}

// ---------------------------------------------------------------------------
// K3: squash s -> v (layout [j][o][b]); optionally write d_out in [j][b][o]
// grid 10, block 256 (thread = b)
// ---------------------------------------------------------------------------
__global__ __launch_bounds__(256) void k_squash(const float* __restrict__ s,
                                                float* __restrict__ v,
                                                float* __restrict__ out,
                                                int write_out) {
    const int j = blockIdx.x, b = threadIdx.x;
    const float* sp = s + (size_t)j * OUT_DIM * BATCH + b;
    float sv[OUT_DIM];
    float m2 = 0.f;
    #pragma unroll
    for (int o = 0; o < OUT_DIM; ++o) { sv[o] = sp[o * BATCH]; m2 += sv[o] * sv[o]; }
    const float scale = sqrtf(m2) / (1.0f + m2);   // == mag_sq/(1+mag_sq) * 1/mag
    float* vp = v + (size_t)j * OUT_DIM * BATCH + b;
    #pragma unroll
    for (int o = 0; o < OUT_DIM; ++o) vp[o * BATCH] = sv[o] * scale;
    if (write_out) {
        float* op = out + ((size_t)j * BATCH + b) * OUT_DIM;
        #pragma unroll
        for (int o = 0; o < OUT_DIM; ++o) op[o] = sv[o] * scale;
    }
}

// ---------------------------------------------------------------------------
// K4: Y_j[o,k] = sum_b v_j[o,b] * x[b,k]
// grid (10 j, 18 k-tiles of 512), block 256; thread handles columns t and t+256
// ---------------------------------------------------------------------------
__global__ __launch_bounds__(256) void k_gemm_Y(const float* __restrict__ x,
                                                const float* __restrict__ v,
                                                float* __restrict__ Y) {
    const int j = blockIdx.x;
    const int k0 = blockIdx.y * 512;
    __shared__ float Vs[BATCH][OUT_DIM];   // [b][o]
    const int t = threadIdx.x;
    const float* vj = v + (size_t)j * OUT_DIM * BATCH;
    #pragma unroll
    for (int o = 0; o < OUT_DIM; ++o) Vs[t][o] = vj[o * BATCH + t];  // coalesced reads
    __syncthreads();

    const int c0 = k0 + t, c1 = k0 + 256 + t;
    float4 acc0[4], acc1[4];
    #pragma unroll
    for (int q = 0; q < 4; ++q) {
        acc0[q] = make_float4(0.f, 0.f, 0.f, 0.f);
        acc1[q] = make_float4(0.f, 0.f, 0.f, 0.f);
    }
    #pragma unroll 4
    for (int b = 0; b < BATCH; ++b) {
        const float xv0 = x[(size_t)b * KTOT + c0];
        const float xv1 = x[(size_t)b * KTOT + c1];
        #pragma unroll
        for (int q = 0; q < 4; ++q) {
            float4 vv = *reinterpret_cast<const float4*>(&Vs[b][q * 4]);  // broadcast
            acc0[q].x += xv0 * vv.x; acc0[q].y += xv0 * vv.y;
            acc0[q].z += xv0 * vv.z; acc0[q].w += xv0 * vv.w;
            acc1[q].x += xv1 * vv.x; acc1[q].y += xv1 * vv.y;
            acc1[q].z += xv1 * vv.z; acc1[q].w += xv1 * vv.w;
        }
    }
    float* Yj = Y + (size_t)j * OUT_DIM * KTOT;
    #pragma unroll
    for (int q = 0; q < 4; ++q) {
        Yj[(size_t)(q * 4 + 0) * KTOT + c0] = acc0[q].x;
        Yj[(size_t)(q * 4 + 1) * KTOT + c0] = acc0[q].y;
        Yj[(size_t)(q * 4 + 2) * KTOT + c0] = acc0[q].z;
        Yj[(size_t)(q * 4 + 3) * KTOT + c0] = acc0[q].w;
        Yj[(size_t)(q * 4 + 0) * KTOT + c1] = acc1[q].x;
        Yj[(size_t)(q * 4 + 1) * KTOT + c1] = acc1[q].y;
        Yj[(size_t)(q * 4 + 2) * KTOT + c1] = acc1[q].z;
        Yj[(size_t)(q * 4 + 3) * KTOT + c1] = acc1[q].w;
    }
}

// ---------------------------------------------------------------------------
// K5: b[i,j] += (1/BATCH) * sum_{o,d} W[i,j,o,d] * Y_j[o, d*IN_NUM + i]
// flat p = j*IN_NUM + i, one thread each
// ---------------------------------------------------------------------------
__global__ __launch_bounds__(256) void k_bupdate(const float* __restrict__ W,
                                                 const float* __restrict__ Y,
                                                 float* __restrict__ b) {
    const int p = blockIdx.x * blockDim.x + threadIdx.x;
    if (p >= IN_NUM * OUT_NUM) return;
    const int j = p / IN_NUM, i = p - j * IN_NUM;
    const float* Wp = W + (size_t)i * 1280 + j * 128;
    const float* Yj = Y + (size_t)j * OUT_DIM * KTOT;
    float acc = 0.f;
    #pragma unroll
    for (int o = 0; o < OUT_DIM; ++o) {
        #pragma unroll
        for (int d = 0; d < IN_DIM; ++d) {
            acc += Wp[o * 8 + d] * Yj[(size_t)o * KTOT + d * IN_NUM + i];
        }
    }
    b[i * OUT_NUM + j] += acc * (1.0f / BATCH);
}

// ---------------------------------------------------------------------------
extern "C" void kernel_launch(void* const* d_in, const int* in_sizes, int n_in,
                              void* d_out, int out_size, void* d_ws, size_t ws_size,
                              hipStream_t stream) {
    const float* x = (const float*)d_in[0];   // [256][8][1152]
    const float* W = (const float*)d_in[1];   // [1152][10][16][8]
    float* out = (float*)d_out;               // [10][256][16]
    float* ws = (float*)d_ws;

    float* b  = ws;                 // 11520
    float* Ct = ws + 11520;         // 11520
    float* s  = ws + 23040;         // 40960
    float* v  = ws + 64000;         // 40960
    float* Y  = ws + 104960;        // 1474560
    float* Wt = ws + 1579520;       // 1474560   (total 3,054,080 floats = 12.2 MB)

    hipMemsetAsync(b, 0, (size_t)IN_NUM * OUT_NUM * sizeof(float), stream);
    k_transpose_W<<<IN_NUM, 128, 0, stream>>>(W, Wt);

    for (int it = 0; it < 3; ++it) {
        k_softmax<<<(IN_NUM + 255) / 256, 256, 0, stream>>>(b, Ct);
        hipMemsetAsync(s, 0, (size_t)OUT_NUM * OUT_DIM * BATCH * sizeof(float), stream);
        k_gemm_s<<<dim3(OUT_NUM, IN_DIM, 4), 256, 0, stream>>>(x, Wt, Ct, s);
        k_squash<<<OUT_NUM, BATCH, 0, stream>>>(s, v, out, it == 2 ? 1 : 0);
        if (it < 2) {
            k_gemm_Y<<<dim3(OUT_NUM, 18), 256, 0, stream>>>(x, v, Y);
            k_bupdate<<<(IN_NUM * OUT_NUM + 255) / 256, 256, 0, stream>>>(W, Y, b);
        }
    }
}

// Round 2
// 131.141 us; speedup vs baseline: 1.8524x; 1.8524x over previous
//
#include <hip/hip_runtime.h>
#include <math.h>

#define IN_NUM 1152
#define IN_DIM 8
#define OUT_NUM 10
#define OUT_DIM 16
#define BATCH 256
#define KTOT 9216            // IN_DIM * IN_NUM; k = d*IN_NUM + i
#define WJ 147456            // 16 * 9216, per-j Wo/Wc/G stride

typedef __attribute__((ext_vector_type(8))) short short8;
typedef __attribute__((ext_vector_type(4))) float f32x4;

__device__ __forceinline__ unsigned short f2bf(float f) {
    unsigned int u = __builtin_bit_cast(unsigned int, f);
    u += 0x7FFF + ((u >> 16) & 1);          // RNE; inputs are well-behaved (no NaN/inf)
    return (unsigned short)(u >> 16);
}
__device__ __forceinline__ float bf2f(unsigned short h) {
    unsigned int u = ((unsigned int)h) << 16;
    return __builtin_bit_cast(float, u);
}

// ---------------------------------------------------------------------------
// P0: W[i][j][o][d] (f32) -> Wo[j][o][k=d*1152+i] (bf16). grid 180 (= 10j x 18 i-tiles)
// ---------------------------------------------------------------------------
__global__ __launch_bounds__(256) void k_prep_w(const float* __restrict__ W,
                                                unsigned short* __restrict__ Wo) {
    const int j  = blockIdx.x / 18;
    const int i0 = (blockIdx.x % 18) * 64;
    __shared__ float Ls[128][65];           // [od][il], pad -> 2-way alias (free)
    const int t = threadIdx.x;
    #pragma unroll 4
    for (int st = 0; st < 32; ++st) {
        const int il = st * 2 + (t >> 7);
        const int od = t & 127;
        Ls[od][il] = W[(size_t)(i0 + il) * 1280 + j * 128 + od];   // coalesced
    }
    __syncthreads();
    #pragma unroll 4
    for (int st = 0; st < 32; ++st) {
        const int od = st * 4 + (t >> 6);
        const int il = t & 63;
        const int o = od >> 3, d = od & 7;
        Wo[(size_t)j * WJ + o * KTOT + d * IN_NUM + i0 + il] = f2bf(Ls[od][il]);
    }
}

// ---------------------------------------------------------------------------
// P1: x[b][k] f32 -> xb[b][k] bf16 AND xT[k][b] bf16. grid (144 ktiles, 4 btiles)
// ---------------------------------------------------------------------------
__global__ __launch_bounds__(256) void k_prep_x(const float* __restrict__ x,
                                                unsigned short* __restrict__ xb,
                                                unsigned short* __restrict__ xT) {
    const int k0 = blockIdx.x * 64;
    const int b0 = blockIdx.y * 64;
    __shared__ float Xs[64][65];            // [k][b]
    const int t = threadIdx.x;
    #pragma unroll 4
    for (int st = 0; st < 16; ++st) {
        const int bl = st * 4 + (t >> 6);
        const int kl = t & 63;
        const float f = x[(size_t)(b0 + bl) * KTOT + k0 + kl];     // coalesced
        Xs[kl][bl] = f;
        xb[(size_t)(b0 + bl) * KTOT + k0 + kl] = f2bf(f);          // coalesced
    }
    __syncthreads();
    #pragma unroll 4
    for (int st = 0; st < 16; ++st) {
        const int kl = st * 4 + (t >> 6);
        const int bl = t & 63;
        xT[(size_t)(k0 + kl) * BATCH + b0 + bl] = f2bf(Xs[kl][bl]); // coalesced
    }
}

// ---------------------------------------------------------------------------
// K1: row softmax of b[i][j] over j -> Ct[j][i]
// ---------------------------------------------------------------------------
__global__ __launch_bounds__(256) void k_softmax(const float* __restrict__ b,
                                                 float* __restrict__ Ct) {
    const int i = blockIdx.x * blockDim.x + threadIdx.x;
    if (i >= IN_NUM) return;
    float v[OUT_NUM];
    float m = -INFINITY;
    for (int j = 0; j < OUT_NUM; ++j) { v[j] = b[i * OUT_NUM + j]; m = fmaxf(m, v[j]); }
    float ssum = 0.f;
    for (int j = 0; j < OUT_NUM; ++j) { v[j] = expf(v[j] - m); ssum += v[j]; }
    const float inv = 1.0f / ssum;
    for (int j = 0; j < OUT_NUM; ++j) Ct[j * IN_NUM + i] = v[j] * inv;
}

// ---------------------------------------------------------------------------
// K2: Wc[j][o][k] = Ct[j][k%1152] * Wo[j][o][k]   (bf16 out). 8 elems/thread.
// ---------------------------------------------------------------------------
__global__ __launch_bounds__(256) void k_wc(const unsigned short* __restrict__ Wo,
                                            const float* __restrict__ Ct,
                                            unsigned short* __restrict__ Wc) {
    const size_t f = ((size_t)blockIdx.x * 256 + threadIdx.x) * 8;   // < 1474560
    const int j  = (int)(f / WJ);
    const int r1 = (int)(f % WJ);
    const int i  = r1 % IN_NUM;              // == k % 1152, no wrap within 8 (1152%8==0)
    const unsigned short* wp = Wo + f;
    const float* cp = Ct + j * IN_NUM + i;
    unsigned short out[8];
    #pragma unroll
    for (int e = 0; e < 8; ++e) out[e] = f2bf(bf2f(wp[e]) * cp[e]);
    *reinterpret_cast<short8*>(Wc + f) = *reinterpret_cast<const short8*>(out);
}

// ---------------------------------------------------------------------------
// K3: s[j][o][b] += sum_k A[j][o][k] * xb[b][k]   via mfma_f32_16x16x32_bf16
// A = Wo (iter0, c uniform) or Wc. 2560 waves = 10j x 16 btiles x 16 k-chunks.
// Fragments loaded directly from global (L2-resident); atomicAdd over k-chunks.
// ---------------------------------------------------------------------------
__global__ __launch_bounds__(256) void k_gemm_s(const unsigned short* __restrict__ A,
                                                const unsigned short* __restrict__ xb,
                                                float* __restrict__ s) {
    const int wid  = blockIdx.x * 4 + (threadIdx.x >> 6);
    const int lane = threadIdx.x & 63;
    const int kc    = wid & 15;
    const int btile = (wid >> 4) & 15;
    const int j     = wid >> 8;              // < 10
    const int row = lane & 15, kg = lane >> 4;

    const unsigned short* ap = A  + (size_t)j * WJ + row * KTOT + kc * 576 + kg * 8;
    const unsigned short* bp = xb + (size_t)(btile * 16 + row) * KTOT + kc * 576 + kg * 8;

    f32x4 acc = {0.f, 0.f, 0.f, 0.f};
    #pragma unroll
    for (int t = 0; t < 18; ++t) {           // 18 * 32 = 576 k per chunk
        short8 a = *reinterpret_cast<const short8*>(ap);
        short8 b = *reinterpret_cast<const short8*>(bp);
        acc = __builtin_amdgcn_mfma_f32_16x16x32_bf16(a, b, acc, 0, 0, 0);
        ap += 32; bp += 32;
    }
    // D: col = lane&15 -> b, row = kg*4 + r -> o   [m89-verified]
    float* sp = s + (size_t)j * OUT_DIM * BATCH + (kg * 4) * BATCH + btile * 16 + row;
    atomicAdd(sp + 0 * BATCH, acc[0]);
    atomicAdd(sp + 1 * BATCH, acc[1]);
    atomicAdd(sp + 2 * BATCH, acc[2]);
    atomicAdd(sp + 3 * BATCH, acc[3]);
}

// ---------------------------------------------------------------------------
// K4: squash s (x scale) -> v bf16 [j][o][b]; optionally d_out f32 [j][b][o]
// ---------------------------------------------------------------------------
__global__ __launch_bounds__(256) void k_squash(const float* __restrict__ s,
                                                unsigned short* __restrict__ vb,
                                                float* __restrict__ out,
                                                float scale, int write_out) {
    const int j = blockIdx.x, b = threadIdx.x;
    const float* sp = s + (size_t)j * OUT_DIM * BATCH + b;
    float sv[OUT_DIM];
    float m2 = 0.f;
    #pragma unroll
    for (int o = 0; o < OUT_DIM; ++o) { sv[o] = sp[o * BATCH] * scale; m2 += sv[o] * sv[o]; }
    const float f = sqrtf(m2) / (1.0f + m2);
    unsigned short* vp = vb + (size_t)j * OUT_DIM * BATCH + b;
    #pragma unroll
    for (int o = 0; o < OUT_DIM; ++o) vp[o * BATCH] = f2bf(sv[o] * f);
    if (write_out) {
        float* op = out + ((size_t)j * BATCH + b) * OUT_DIM;
        #pragma unroll
        for (int o = 0; o < OUT_DIM; ++o) op[o] = sv[o] * f;
    }
}

// ---------------------------------------------------------------------------
// K5: G[j][k][o] = sum_b xT[k][b] * v[o][b]   via mfma. 5760 waves (576 ktiles x 10 j).
// A row = xT k-row (b-contig), B col = o from vb[j][o][b] (b-contig). No split.
// ---------------------------------------------------------------------------
__global__ __launch_bounds__(256) void k_gemm_G(const unsigned short* __restrict__ xT,
                                                const unsigned short* __restrict__ vb,
                                                float* __restrict__ G) {
    const int wid  = blockIdx.x * 4 + (threadIdx.x >> 6);
    const int lane = threadIdx.x & 63;
    const int j  = wid % 10;
    const int kt = wid / 10;                 // < 576
    const int rc = lane & 15, kg = lane >> 4;

    const unsigned short* ap = xT + (size_t)(kt * 16 + rc) * BATCH + kg * 8;
    const unsigned short* bp = vb + (size_t)j * OUT_DIM * BATCH + rc * BATCH + kg * 8;

    f32x4 acc = {0.f, 0.f, 0.f, 0.f};
    #pragma unroll
    for (int bb = 0; bb < 8; ++bb) {         // 8 * 32 = 256 = BATCH
        short8 a = *reinterpret_cast<const short8*>(ap + bb * 32);
        short8 b = *reinterpret_cast<const short8*>(bp + bb * 32);
        acc = __builtin_amdgcn_mfma_f32_16x16x32_bf16(a, b, acc, 0, 0, 0);
    }
    // D: col = lane&15 -> o, row = kg*4 + r -> k-row within tile
    float* gp = G + (size_t)j * WJ + (size_t)(kt * 16 + kg * 4) * OUT_DIM + rc;
    #pragma unroll
    for (int r = 0; r < 4; ++r) gp[r * OUT_DIM] = acc[r];
}

// ---------------------------------------------------------------------------
// K6: b[i,j] += (1/256) * sum_{o,d} W[i,j,o,d] * G[j][d*1152+i][o]
// ---------------------------------------------------------------------------
__global__ __launch_bounds__(256) void k_bupdate(const float* __restrict__ W,
                                                 const float* __restrict__ G,
                                                 float* __restrict__ b) {
    const int p = blockIdx.x * 256 + threadIdx.x;    // < 11520
    const int j = p / IN_NUM, i = p - j * IN_NUM;
    const float* Wp = W + (size_t)i * 1280 + j * 128;
    const float* Gj = G + (size_t)j * WJ;
    float acc = 0.f;
    #pragma unroll
    for (int d = 0; d < IN_DIM; ++d) {
        const float* gr = Gj + (size_t)(d * IN_NUM + i) * OUT_DIM;
        float4 g0 = *reinterpret_cast<const float4*>(gr + 0);
        float4 g1 = *reinterpret_cast<const float4*>(gr + 4);
        float4 g2 = *reinterpret_cast<const float4*>(gr + 8);
        float4 g3 = *reinterpret_cast<const float4*>(gr + 12);
        acc += Wp[0 * 8 + d] * g0.x + Wp[1 * 8 + d] * g0.y
             + Wp[2 * 8 + d] * g0.z + Wp[3 * 8 + d] * g0.w
             + Wp[4 * 8 + d] * g1.x + Wp[5 * 8 + d] * g1.y
             + Wp[6 * 8 + d] * g1.z + Wp[7 * 8 + d] * g1.w
             + Wp[8 * 8 + d] * g2.x + Wp[9 * 8 + d] * g2.y
             + Wp[10 * 8 + d] * g2.z + Wp[11 * 8 + d] * g2.w
             + Wp[12 * 8 + d] * g3.x + Wp[13 * 8 + d] * g3.y
             + Wp[14 * 8 + d] * g3.z + Wp[15 * 8 + d] * g3.w;
    }
    b[i * OUT_NUM + j] += acc * (1.0f / BATCH);
}

// ---------------------------------------------------------------------------
extern "C" void kernel_launch(void* const* d_in, const int* in_sizes, int n_in,
                              void* d_out, int out_size, void* d_ws, size_t ws_size,
                              hipStream_t stream) {
    const float* x = (const float*)d_in[0];   // [256][8][1152]
    const float* W = (const float*)d_in[1];   // [1152][10][16][8]
    float* out = (float*)d_out;               // [10][256][16]
    float* ws = (float*)d_ws;

    float*          b  = ws;                                   // 11520 f32
    float*          Ct = ws + 11520;                           // 11520 f32
    float*          s  = ws + 23040;                           // 40960 f32
    float*          G  = ws + 64000;                           // 1474560 f32
    unsigned short* Wo = (unsigned short*)(ws + 1538560);      // 1474560 bf16
    unsigned short* Wc = (unsigned short*)(ws + 2275840);      // 1474560 bf16
    unsigned short* xb = (unsigned short*)(ws + 3013120);      // 2359296 bf16
    unsigned short* xT = (unsigned short*)(ws + 4192768);      // 2359296 bf16
    unsigned short* vb = (unsigned short*)(ws + 5372416);      // 40960 bf16
    // total: 5392896 f32 = 21.6 MB

    hipMemsetAsync(b, 0, (size_t)IN_NUM * OUT_NUM * sizeof(float), stream);
    k_prep_w<<<180, 256, 0, stream>>>(W, Wo);
    k_prep_x<<<dim3(144, 4), 256, 0, stream>>>(x, xb, xT);

    for (int it = 0; it < 3; ++it) {
        const unsigned short* A = Wo;        // iter 0: c == 0.1 uniform, fold into squash
        if (it > 0) {
            k_softmax<<<5, 256, 0, stream>>>(b, Ct);
            k_wc<<<720, 256, 0, stream>>>(Wo, Ct, Wc);
            A = Wc;
        }
        hipMemsetAsync(s, 0, (size_t)OUT_NUM * OUT_DIM * BATCH * sizeof(float), stream);
        k_gemm_s<<<640, 256, 0, stream>>>(A, xb, s);
        k_squash<<<OUT_NUM, BATCH, 0, stream>>>(s, vb, out,
                                                it == 0 ? 0.1f : 1.0f, it == 2 ? 1 : 0);
        if (it < 2) {
            k_gemm_G<<<1440, 256, 0, stream>>>(xT, vb, G);
            k_bupdate<<<45, 256, 0, stream>>>(W, G, b);
        }
    }
}

// Round 3
// 112.458 us; speedup vs baseline: 2.1602x; 1.1661x over previous
//
#include <hip/hip_runtime.h>
#include <math.h>

#define IN_NUM 1152
#define IN_DIM 8
#define OUT_NUM 10
#define OUT_DIM 16
#define BATCH 256
#define KTOT 9216            // IN_DIM * IN_NUM; k = d*IN_NUM + i
#define WJ 147456            // 16 * 9216, per-j Wo/Wc stride

typedef __attribute__((ext_vector_type(8))) short short8;
typedef __attribute__((ext_vector_type(4))) short short4v;
typedef __attribute__((ext_vector_type(4))) float f32x4;

__device__ __forceinline__ unsigned short f2bf(float f) {
    unsigned int u = __builtin_bit_cast(unsigned int, f);
    u += 0x7FFF + ((u >> 16) & 1);          // RNE
    return (unsigned short)(u >> 16);
}
__device__ __forceinline__ float bf2f(unsigned short h) {
    unsigned int u = ((unsigned int)h) << 16;
    return __builtin_bit_cast(float, u);
}

// ---------------------------------------------------------------------------
// P: fused prep.  blocks [0,180): W[i][j][o][d] f32 -> Wo[j][o][k=d*1152+i] bf16
//                 blocks [180,756): x f32 -> xb[b][k] bf16 and xT[k][b] bf16
// ---------------------------------------------------------------------------
__global__ __launch_bounds__(256) void k_prep(const float* __restrict__ W,
                                              const float* __restrict__ x,
                                              unsigned short* __restrict__ Wo,
                                              unsigned short* __restrict__ xb,
                                              unsigned short* __restrict__ xT) {
    __shared__ float Ls[128 * 65];
    const int t = threadIdx.x;
    if (blockIdx.x < 180) {
        const int j  = blockIdx.x / 18;
        const int i0 = (blockIdx.x % 18) * 64;
        #pragma unroll 4
        for (int st = 0; st < 32; ++st) {
            const int il = st * 2 + (t >> 7);
            const int od = t & 127;
            Ls[il * 130 + od] = W[(size_t)(i0 + il) * 1280 + j * 128 + od]; // coalesced
        }
        __syncthreads();
        #pragma unroll 4
        for (int st = 0; st < 32; ++st) {
            const int od = st * 4 + (t >> 6);
            const int il = t & 63;
            const int o = od >> 3, d = od & 7;
            Wo[(size_t)j * WJ + o * KTOT + d * IN_NUM + i0 + il] = f2bf(Ls[il * 130 + od]);
        }
    } else {
        const int bx = blockIdx.x - 180;
        const int k0 = (bx >> 2) * 64;
        const int b0 = (bx & 3) * 64;
        #pragma unroll 4
        for (int st = 0; st < 16; ++st) {
            const int bl = st * 4 + (t >> 6);
            const int kl = t & 63;
            const float f = x[(size_t)(b0 + bl) * KTOT + k0 + kl];         // coalesced
            Ls[kl * 65 + bl] = f;
            xb[(size_t)(b0 + bl) * KTOT + k0 + kl] = f2bf(f);              // coalesced
        }
        __syncthreads();
        #pragma unroll 4
        for (int st = 0; st < 16; ++st) {
            const int kl = st * 4 + (t >> 6);
            const int bl = t & 63;
            xT[(size_t)(k0 + kl) * BATCH + b0 + bl] = f2bf(Ls[kl * 65 + bl]);
        }
    }
}

// ---------------------------------------------------------------------------
// S: fused GEMM-s + squash.  block = (j, btile): 4 waves split K=9216 into 2304
// chunks (72 MFMA each), LDS-reduce, squash in epilogue. Exclusive ownership:
// no atomics, no zero-init. Writes vb bf16 [j][o][b]; last iter also d_out.
// ---------------------------------------------------------------------------
__global__ __launch_bounds__(256) void k_gemm_sq(const unsigned short* __restrict__ A,
                                                 const unsigned short* __restrict__ xb,
                                                 unsigned short* __restrict__ vb,
                                                 float* __restrict__ out,
                                                 float scale, int wout) {
    const int j     = blockIdx.x >> 4;
    const int btile = blockIdx.x & 15;
    const int w    = threadIdx.x >> 6;
    const int lane = threadIdx.x & 63;
    const int row = lane & 15, kg = lane >> 4;

    const unsigned short* ap = A  + (size_t)j * WJ + row * KTOT + w * 2304 + kg * 8;
    const unsigned short* bp = xb + (size_t)(btile * 16 + row) * KTOT + w * 2304 + kg * 8;

    f32x4 acc = {0.f, 0.f, 0.f, 0.f};
    #pragma unroll 8
    for (int it = 0; it < 72; ++it) {        // 72 * 32 = 2304 k per wave
        short8 a = *reinterpret_cast<const short8*>(ap);
        short8 b = *reinterpret_cast<const short8*>(bp);
        acc = __builtin_amdgcn_mfma_f32_16x16x32_bf16(a, b, acc, 0, 0, 0);
        ap += 32; bp += 32;
    }
    // D: col(lane&15) -> b, row kg*4+r -> o
    __shared__ float Sred[4][16][16];        // [wave][o][b]
    __shared__ float fs[16];
    #pragma unroll
    for (int r = 0; r < 4; ++r) Sred[w][kg * 4 + r][row] = acc[r];
    __syncthreads();

    const int o = threadIdx.x >> 4, b = threadIdx.x & 15;
    float sum = Sred[0][o][b] + Sred[1][o][b] + Sred[2][o][b] + Sred[3][o][b];
    Sred[0][o][b] = sum;                     // own slot, no race
    __syncthreads();
    float m2r = 0.f;
    #pragma unroll
    for (int oo = 0; oo < 16; ++oo) { const float q = Sred[0][oo][b]; m2r += q * q; }
    const float m2 = m2r * scale * scale;
    const float f  = sqrtf(m2) / (1.0f + m2);
    vb[(size_t)j * OUT_DIM * BATCH + o * BATCH + btile * 16 + b] = f2bf(sum * scale * f);
    if (wout) {
        if (o == 0) fs[b] = f;
        __syncthreads();
        const int b2 = threadIdx.x >> 4, o2 = threadIdx.x & 15;
        out[((size_t)j * BATCH + btile * 16 + b2) * OUT_DIM + o2] =
            Sred[0][o2][b2] * scale * fs[b2];   // coalesced f32
    }
}

// ---------------------------------------------------------------------------
// G: fused GEMM-G + b-partial.  wave = (j, ktile): G[k][o] fragment in regs,
// epilogue multiplies by Wo[j][o][k], shfl-reduces over o, writes bp[j][k].
// G never materialized. Exclusive per (j,ktile) -> no init needed.
// ---------------------------------------------------------------------------
__global__ __launch_bounds__(256) void k_gemm_Gb(const unsigned short* __restrict__ xT,
                                                 const unsigned short* __restrict__ vb,
                                                 const unsigned short* __restrict__ Wo,
                                                 float* __restrict__ bp) {
    const int wid  = blockIdx.x * 4 + (threadIdx.x >> 6);
    const int lane = threadIdx.x & 63;
    const int j  = wid % 10;
    const int kt = wid / 10;                 // < 576
    const int rc = lane & 15, kg = lane >> 4;

    const unsigned short* ap = xT + (size_t)(kt * 16 + rc) * BATCH + kg * 8;
    const unsigned short* vp = vb + (size_t)j * OUT_DIM * BATCH + rc * BATCH + kg * 8;

    f32x4 acc = {0.f, 0.f, 0.f, 0.f};
    #pragma unroll
    for (int bb = 0; bb < 8; ++bb) {         // 8 * 32 = 256 = BATCH
        short8 a = *reinterpret_cast<const short8*>(ap + bb * 32);
        short8 b = *reinterpret_cast<const short8*>(vp + bb * 32);
        acc = __builtin_amdgcn_mfma_f32_16x16x32_bf16(a, b, acc, 0, 0, 0);
    }
    // lane(rc,kg) holds G[k = kt*16 + kg*4 + r][o = rc]
    const int kbase = kt * 16 + kg * 4;
    short4v w4 = *reinterpret_cast<const short4v*>(
        Wo + (size_t)j * WJ + rc * KTOT + kbase);
    float p[4];
    #pragma unroll
    for (int r = 0; r < 4; ++r) p[r] = acc[r] * bf2f((unsigned short)w4[r]);
    #pragma unroll
    for (int m = 1; m < 16; m <<= 1) {
        #pragma unroll
        for (int r = 0; r < 4; ++r) p[r] += __shfl_xor(p[r], m);
    }
    if (rc == 0) {
        float4 v4 = make_float4(p[0], p[1], p[2], p[3]);
        *reinterpret_cast<float4*>(bp + (size_t)j * KTOT + kbase) = v4;
    }
}

// ---------------------------------------------------------------------------
// B: softmax from partials.  logit[i][j] (+)= sum_d bp[j][d*1152+i] / 256,
// carried in blog across iterations; writes Ct[j][i] f32.
// ---------------------------------------------------------------------------
__global__ __launch_bounds__(256) void k_softmaxb(const float* __restrict__ bp,
                                                  float* __restrict__ blog,
                                                  float* __restrict__ Ct,
                                                  int first) {
    const int i = blockIdx.x * blockDim.x + threadIdx.x;
    if (i >= IN_NUM) return;
    float lg[OUT_NUM];
    float m = -INFINITY;
    for (int j = 0; j < OUT_NUM; ++j) {
        float a = first ? 0.f : blog[i * OUT_NUM + j];
        float s = 0.f;
        #pragma unroll
        for (int d = 0; d < IN_DIM; ++d) s += bp[(size_t)j * KTOT + d * IN_NUM + i];
        a += s * (1.0f / BATCH);
        lg[j] = a; blog[i * OUT_NUM + j] = a;
        m = fmaxf(m, a);
    }
    float ssum = 0.f;
    for (int j = 0; j < OUT_NUM; ++j) { lg[j] = expf(lg[j] - m); ssum += lg[j]; }
    const float inv = 1.0f / ssum;
    for (int j = 0; j < OUT_NUM; ++j) Ct[j * IN_NUM + i] = lg[j] * inv;
}

// ---------------------------------------------------------------------------
// C: Wc[j][o][k] = Ct[j][k%1152] * Wo[j][o][k]  (bf16). 8 elems/thread.
// ---------------------------------------------------------------------------
__global__ __launch_bounds__(256) void k_wc(const unsigned short* __restrict__ Wo,
                                            const float* __restrict__ Ct,
                                            unsigned short* __restrict__ Wc) {
    const size_t f = ((size_t)blockIdx.x * 256 + threadIdx.x) * 8;   // < 1474560
    const int j  = (int)(f / WJ);
    const int i  = (int)(f % WJ) % IN_NUM;   // 8-chunk never crosses i-wrap (1152%8==0)
    const unsigned short* wp = Wo + f;
    const float* cp = Ct + j * IN_NUM + i;
    unsigned short outv[8];
    #pragma unroll
    for (int e = 0; e < 8; ++e) outv[e] = f2bf(bf2f(wp[e]) * cp[e]);
    *reinterpret_cast<short8*>(Wc + f) = *reinterpret_cast<const short8*>(outv);
}

// ---------------------------------------------------------------------------
extern "C" void kernel_launch(void* const* d_in, const int* in_sizes, int n_in,
                              void* d_out, int out_size, void* d_ws, size_t ws_size,
                              hipStream_t stream) {
    const float* x = (const float*)d_in[0];   // [256][8][1152]
    const float* W = (const float*)d_in[1];   // [1152][10][16][8]
    float* out = (float*)d_out;               // [10][256][16]
    float* ws = (float*)d_ws;

    float*          blog = ws;                                 // 11520 f32
    float*          Ct   = ws + 11520;                         // 11520 f32
    float*          bpb  = ws + 23040;                         // 92160 f32 (bp)
    unsigned short* vb   = (unsigned short*)(ws + 115200);     // 40960 bf16
    unsigned short* Wo   = (unsigned short*)(ws + 135680);     // 1474560 bf16
    unsigned short* Wc   = (unsigned short*)(ws + 872960);     // 1474560 bf16
    unsigned short* xb   = (unsigned short*)(ws + 1610240);    // 2359296 bf16
    unsigned short* xT   = (unsigned short*)(ws + 2789888);    // 2359296 bf16
    // end: 3969536 f32 = 15.9 MB

    k_prep<<<756, 256, 0, stream>>>(W, x, Wo, xb, xT);

    // iter 0: c uniform = 0.1, folded into squash scale; no softmax/wc
    k_gemm_sq<<<160, 256, 0, stream>>>(Wo, xb, vb, out, 0.1f, 0);
    k_gemm_Gb<<<1440, 256, 0, stream>>>(xT, vb, Wo, bpb);

    // iter 1
    k_softmaxb<<<5, 256, 0, stream>>>(bpb, blog, Ct, 1);
    k_wc<<<720, 256, 0, stream>>>(Wo, Ct, Wc);
    k_gemm_sq<<<160, 256, 0, stream>>>(Wc, xb, vb, out, 1.0f, 0);
    k_gemm_Gb<<<1440, 256, 0, stream>>>(xT, vb, Wo, bpb);

    // iter 2 (final): writes d_out
    k_softmaxb<<<5, 256, 0, stream>>>(bpb, blog, Ct, 0);
    k_wc<<<720, 256, 0, stream>>>(Wo, Ct, Wc);
    k_gemm_sq<<<160, 256, 0, stream>>>(Wc, xb, vb, out, 1.0f, 1);
}